// Round 6
// baseline (69.456 us; speedup 1.0000x reference)
//
#include <hip/hip_runtime.h>

// Problem constants (from reference setup_inputs)
#define B_    8
#define C_    3
#define O_    8
#define H_    128
#define W_    128
#define KS_   5
#define HO_   (H_ - KS_ + 1)   // 124
#define WO_   (W_ - KS_ + 1)   // 124
#define NPIX  (HO_ * WO_)      // 15376
#define NTAP  (KS_ * KS_)      // 25
#define PX    4                 // pixels per thread along wo (124 = 31*4)
#define NG    (WO_ / PX)        // 31 groups per row
#define NPIXG (HO_ * NG)        // 3844 per (b,c)
#define BLK   256

typedef float floatx4 __attribute__((ext_vector_type(4)));  // native vec for nontemporal builtins

// grid.y = b*C + c ; grid.x tiles the (ho, wo-group) space.
// K reads are wave-uniform (c from blockIdx.y, o/t unrolled constants) ->
// s_load into SGPRs; inner loop is pure VALU. Pair-wise min/max tree coaxes
// v_min3_f32/v_max3_f32 (25 sub + 12 min3 per chain instead of 25 sub + 24 min).
__global__ __launch_bounds__(BLK)
void mnn_kernel(const float* __restrict__ x,
                const float* __restrict__ Kh,
                const float* __restrict__ Km,
                float* __restrict__ out)
{
    const int bc = blockIdx.y;
    const int b  = bc / C_;
    const int c  = bc % C_;

    const int p = blockIdx.x * BLK + threadIdx.x;
    if (p >= NPIXG) return;
    const int ho  = p / NG;
    const int wo0 = (p % NG) * PX;   // multiple of 4 -> 16B-aligned float4

    // Load the 5x8 x-window into registers as float4s (cols wo0..wo0+7)
    float w[KS_][KS_ + PX - 1];      // [5][8]
    const float* xrow = x + ((b * C_ + c) * H_ + ho) * W_ + wo0;
#pragma unroll
    for (int u = 0; u < KS_; ++u) {
#pragma unroll
        for (int v4 = 0; v4 < 2; ++v4) {
            const floatx4 t = *reinterpret_cast<const floatx4*>(xrow + u * W_ + v4 * 4);
            w[u][v4 * 4 + 0] = t.x;
            w[u][v4 * 4 + 1] = t.y;
            w[u][v4 * 4 + 2] = t.z;
            w[u][v4 * 4 + 3] = t.w;
        }
    }

    const float* khc = Kh + c * NTAP;
    const float* kmc = Km + c * NTAP;

    const size_t obase = ((size_t)b * (O_ * C_) + c) * (size_t)NPIX
                       + (size_t)ho * WO_ + wo0;

#pragma unroll
    for (int o = 0; o < O_; ++o) {
        const float* kh = khc + o * (C_ * NTAP);
        const float* km = kmc + o * (C_ * NTAP);

        float hit[PX], miss[PX];
        // tap 0 seeds the chains
        {
            const float kh0 = kh[0], km0 = km[0];
#pragma unroll
            for (int q = 0; q < PX; ++q) {
                hit[q]  = w[0][q] - kh0;
                miss[q] = w[0][q] - km0;
            }
        }
        // taps 1..24 in pairs -> fminf(fminf(acc,a),b) fuses to v_min3_f32
#pragma unroll
        for (int t = 1; t < NTAP; t += 2) {
            const int u0 = t / KS_,       v0 = t % KS_;
            const int u1 = (t + 1) / KS_, v1 = (t + 1) % KS_;
            const float kh0 = kh[t], kh1 = kh[t + 1];
            const float km0 = km[t], km1 = km[t + 1];
#pragma unroll
            for (int q = 0; q < PX; ++q) {
                hit[q]  = fminf(fminf(hit[q],  w[u0][v0 + q] - kh0), w[u1][v1 + q] - kh1);
                miss[q] = fmaxf(fmaxf(miss[q], w[u0][v0 + q] - km0), w[u1][v1 + q] - km1);
            }
        }

        floatx4 r;
        r.x = hit[0] - miss[0];
        r.y = hit[1] - miss[1];
        r.z = hit[2] - miss[2];
        r.w = hit[3] - miss[3];
        __builtin_nontemporal_store(r,
            reinterpret_cast<floatx4*>(out + obase + (size_t)o * (C_ * NPIX)));
    }
}

extern "C" void kernel_launch(void* const* d_in, const int* in_sizes, int n_in,
                              void* d_out, int out_size, void* d_ws, size_t ws_size,
                              hipStream_t stream)
{
    const float* x  = (const float*)d_in[0];
    const float* Kh = (const float*)d_in[1];
    const float* Km = (const float*)d_in[2];
    float* out = (float*)d_out;

    dim3 grid((NPIXG + BLK - 1) / BLK, B_ * C_);
    dim3 block(BLK);
    mnn_kernel<<<grid, block, 0, stream>>>(x, Kh, Km, out);
}